// Round 1
// baseline (4828.698 us; speedup 1.0000x reference)
//
#include <hip/hip_runtime.h>
#include <cstdint>
#include <cstddef>

// Autoregressive 3-layer LSTM, B=512, T=75, IN=96, H=1024, bf16 MFMA compute.
// Per step: 3x fused [GEMM(gates)+LSTM cell] + FC(1024->96)+hardtanh.
// Activation buffers Abuf[l][parity] hold concatenated [xi | h_l] in bf16 so
// each GEMM is a single K-loop; cell epilogue writes h directly into the
// next consumers' buffers. c state stays f32. Weights packed bf16 once per launch.
//
// R1: 4-buffer LDS ring, prefetch depth 3, counted vmcnt(18) — weights are
// L3-resident (43MB > 32MB L2 aggregate), depth-1 prefetch could not cover
// ~600cy L3 latency at 1 wave/SIMD occupancy.

typedef unsigned short u16;
typedef float v4f __attribute__((ext_vector_type(4)));
typedef short v8s __attribute__((ext_vector_type(8)));    // 8 bf16 (4 VGPRs)
typedef u16   v8u16 __attribute__((ext_vector_type(8)));

#define BATCH 512
#define H_DIM 1024
#define GATES 4096
#define T_STEPS 75
#define IN_DIM 96
#define K0P 1152              // layer0 K padded: 96 + 1024 + 32 zeros
#define K12 2048              // layers 1,2 K: 1024 + 1024

__device__ __forceinline__ float bf2f(u16 u) {
    unsigned int x = ((unsigned int)u) << 16;
    return __builtin_bit_cast(float, x);
}
__device__ __forceinline__ u16 f2bf(float f) {   // round-to-nearest-even
    unsigned int x = __builtin_bit_cast(unsigned int, f);
    x += 0x7fffu + ((x >> 16) & 1u);
    return (u16)(x >> 16);
}
__device__ __forceinline__ void gload16(const void* g, void* l) {
    __builtin_amdgcn_global_load_lds(
        (const __attribute__((address_space(1))) void*)g,
        (__attribute__((address_space(3))) void*)l, 16, 0, 0);
}

// ================= fused gates-GEMM + LSTM cell =================
// C[512][4096] = A[512][K] @ W[4096][K]^T + bias, gate-grouped tiles:
// block tile = 64 rows x (4 gates x 32 j). Then cell epilogue:
// c' = sig(f)*c + sig(i)*tanh(g); h = sig(o)*tanh(c'); h -> h1 (+h2) as bf16.
// Pipelined: BK=64, 4-deep LDS ring, depth-3 prefetch, counted vmcnt(18),
// raw s_barrier, XOR-swizzled LDS (involution on 16B chunks within 128B row).
__global__ __launch_bounds__(256, 1) void lstm_layer_k(
    const u16* __restrict__ A, const u16* __restrict__ W, int K, int nsteps,
    const float* __restrict__ bias, float* __restrict__ c,
    u16* __restrict__ h1, int h1s, u16* __restrict__ h2, int h2s)
{
    __shared__ __align__(16) char smem[98304];
    u16* sA = (u16*)smem;              // 4 bufs x 4096 u16 (64x64, 8KB each) = 32KB
    u16* sB = (u16*)(smem + 32768);    // 4 bufs x 8192 u16 (128x64, 16KB each) = 64KB

    const int tid  = threadIdx.x;
    const int lane = tid & 63;
    const int wid  = tid >> 6;
    const int wm   = (wid >> 1) * 32;   // wave m-offset
    const int wn   = (wid & 1) * 64;    // wave n-offset
    const int l15  = lane & 15;
    const int lq   = lane >> 4;         // 0..3

    // XCD swizzle: 8 m-blocks sharing a W-panel land on one XCD
    const int id    = blockIdx.x;
    const int panel = (id & 7) * 4 + (id >> 6);   // 0..31  (j-panel)
    const int mblk  = (id >> 3) & 7;              // 0..7
    const int bm    = mblk * 64;
    const int j0    = panel * 32;

    v4f acc[2][4];
    #pragma unroll
    for (int nf = 0; nf < 4; ++nf) {
        const int ncol = wn + nf * 16 + l15;                    // 0..127
        const float bv = bias[(ncol >> 5) * H_DIM + j0 + (ncol & 31)];
        v4f t = {bv, bv, bv, bv};
        acc[0][nf] = t; acc[1][nf] = t;
    }

    const int srow = tid >> 3;                                   // 0..31
    const int kcs  = ((tid & 7) ^ (srow & 7)) << 3;              // swizzled src k-elem

    auto stage = [&](int b, int k0) {
        u16* sa = sA + b * 4096;
        u16* sb = sB + b * 8192;
        gload16(A + (size_t)(bm + srow) * K + k0 + kcs,      sa + tid * 8);
        gload16(A + (size_t)(bm + 32 + srow) * K + k0 + kcs, sa + 2048 + tid * 8);
        #pragma unroll
        for (int q = 0; q < 4; ++q)   // W rows: gate q, j0 + srow
            gload16(W + (size_t)(q * H_DIM + j0 + srow) * K + k0 + kcs,
                    sb + q * 2048 + tid * 8);
    };

    // depth-3 prologue: 3 buffers in flight before first compute
    {
        const int npre = nsteps < 3 ? nsteps : 3;
        for (int p = 0; p < npre; ++p) stage(p, p * 64);
    }

    #pragma unroll 1
    for (int t = 0; t < nsteps; ++t) {
        const int cur = t & 3;
        if (t + 3 < nsteps) stage((t + 3) & 3, (t + 3) * 64);
        // wait for buffer t's 6 loads; keep up to 3 newer stages in flight
        const int ahead = (nsteps - 1 - t) < 3 ? (nsteps - 1 - t) : 3;
        if (ahead == 3)      asm volatile("s_waitcnt vmcnt(18)" ::: "memory");
        else if (ahead == 2) asm volatile("s_waitcnt vmcnt(12)" ::: "memory");
        else if (ahead == 1) asm volatile("s_waitcnt vmcnt(6)"  ::: "memory");
        else                 asm volatile("s_waitcnt vmcnt(0)"  ::: "memory");
        asm volatile("s_barrier" ::: "memory");

        const char* sa = (const char*)(sA + cur * 4096);
        const char* sb = (const char*)(sB + cur * 8192);
        v8s af[2][2], bfr[4][2];
        #pragma unroll
        for (int mf = 0; mf < 2; ++mf)
            #pragma unroll
            for (int ks = 0; ks < 2; ++ks) {
                const int row = wm + mf * 16 + l15;
                const int ch  = ks * 4 + lq;
                af[mf][ks] = *(const v8s*)(sa + row * 128 + (((ch ^ (row & 7))) << 4));
            }
        #pragma unroll
        for (int nf = 0; nf < 4; ++nf)
            #pragma unroll
            for (int ks = 0; ks < 2; ++ks) {
                const int row = wn + nf * 16 + l15;
                const int ch  = ks * 4 + lq;
                bfr[nf][ks] = *(const v8s*)(sb + row * 128 + (((ch ^ (row & 7))) << 4));
            }
        #pragma unroll
        for (int ks = 0; ks < 2; ++ks)
            #pragma unroll
            for (int mf = 0; mf < 2; ++mf)
                #pragma unroll
                for (int nf = 0; nf < 4; ++nf)
                    acc[mf][nf] = __builtin_amdgcn_mfma_f32_16x16x32_bf16(
                        af[mf][ks], bfr[nf][ks], acc[mf][nf], 0, 0, 0);
        asm volatile("s_barrier" ::: "memory");
    }

    // ---- epilogue: gates -> LDS, then cell ----
    float* sG = (float*)smem;   // [64][132] f32 = 33792B (reuses staging LDS)
    #pragma unroll
    for (int mf = 0; mf < 2; ++mf)
        #pragma unroll
        for (int nf = 0; nf < 4; ++nf)
            #pragma unroll
            for (int r = 0; r < 4; ++r)
                sG[(wm + mf * 16 + lq * 4 + r) * 132 + wn + nf * 16 + l15] =
                    acc[mf][nf][r];
    __syncthreads();

    const int row = tid >> 2;            // 0..63
    const int jj  = (tid & 3) * 8;       // 0,8,16,24
    const int gb  = bm + row;
    const float* sGr = sG + row * 132;
    float* crow = c + (size_t)gb * H_DIM + j0 + jj;
    v4f c0 = *(const v4f*)crow;
    v4f c1 = *(const v4f*)(crow + 4);
    v4f n0, n1;
    v8u16 hv;
    #pragma unroll
    for (int q = 0; q < 8; ++q) {
        const float gi = sGr[      jj + q];
        const float gf = sGr[32  + jj + q];
        const float gg = sGr[64  + jj + q];
        const float go = sGr[96  + jj + q];
        const float cv = (q < 4) ? c0[q] : c1[q - 4];
        const float ii = 1.f / (1.f + __expf(-gi));
        const float ff = 1.f / (1.f + __expf(-gf));
        const float g2 = tanhf(gg);
        const float oo = 1.f / (1.f + __expf(-go));
        const float cq = ff * cv + ii * g2;
        if (q < 4) n0[q] = cq; else n1[q - 4] = cq;
        hv[q] = f2bf(oo * tanhf(cq));
    }
    *(v4f*)crow       = n0;
    *(v4f*)(crow + 4) = n1;
    *(v8u16*)(h1 + (size_t)gb * h1s + j0 + jj) = hv;
    if (h2)
        *(v8u16*)(h2 + (size_t)gb * h2s + j0 + jj) = hv;
}

// ================= FC 1024->96 + hardtanh =================
__global__ __launch_bounds__(128) void fc_k(
    const u16* __restrict__ h2, int h2stride,
    const u16* __restrict__ w, const float* __restrict__ fcb,
    float* __restrict__ out, u16* __restrict__ xdst, int t)
{
    __shared__ float sh[H_DIM];
    const int b = blockIdx.x, tid = threadIdx.x;
    v8u16 hv = *(const v8u16*)(h2 + (size_t)b * h2stride + tid * 8);
    #pragma unroll
    for (int q = 0; q < 8; ++q) sh[tid * 8 + q] = bf2f(hv[q]);
    __syncthreads();
    if (tid < IN_DIM) {
        const u16* wr = w + (size_t)tid * H_DIM;
        float acc = fcb[tid];
        #pragma unroll 4
        for (int k = 0; k < H_DIM; k += 8) {
            v8u16 wv = *(const v8u16*)(wr + k);
            #pragma unroll
            for (int q = 0; q < 8; ++q) acc += sh[k + q] * bf2f(wv[q]);
        }
        acc = fminf(1.f, fmaxf(-1.f, acc));
        out[(size_t)b * (T_STEPS * IN_DIM) + t * IN_DIM + tid] = acc;
        xdst[(size_t)b * K0P + tid] = f2bf(acc);
    }
}

// ================= prologue =================
// f32 [rows][srcStride] -> bf16 [rows][dstStride], cols multiple of 8
__global__ __launch_bounds__(256) void convpack_k(
    const float* __restrict__ src, int srcStride,
    u16* __restrict__ dst, int dstStride, int cols8, long total8)
{
    long i = (long)blockIdx.x * 256 + threadIdx.x;
    if (i >= total8) return;
    const int r  = (int)(i / cols8);
    const int cc = (int)(i - (long)r * cols8) * 8;
    const float* s = src + (size_t)r * srcStride + cc;
    v4f a = *(const v4f*)s;
    v4f b = *(const v4f*)(s + 4);
    v8u16 o;
    #pragma unroll
    for (int q = 0; q < 4; ++q) { o[q] = f2bf(a[q]); o[4 + q] = f2bf(b[q]); }
    *(v8u16*)(dst + (size_t)r * dstStride + cc) = o;
}

__global__ __launch_bounds__(256) void zero16_k(
    u16* __restrict__ dst, int dstStride, int cols8, long total8)
{
    long i = (long)blockIdx.x * 256 + threadIdx.x;
    if (i >= total8) return;
    const int r  = (int)(i / cols8);
    const int cc = (int)(i - (long)r * cols8) * 8;
    v8u16 z = {0, 0, 0, 0, 0, 0, 0, 0};
    *(v8u16*)(dst + (size_t)r * dstStride + cc) = z;
}

__global__ __launch_bounds__(256) void add_k(
    const float* __restrict__ a, const float* __restrict__ b,
    float* __restrict__ o, int n)
{
    int i = blockIdx.x * 256 + threadIdx.x;
    if (i < n) o[i] = a[i] + b[i];
}

extern "C" void kernel_launch(void* const* d_in, const int* in_sizes, int n_in,
                              void* d_out, int out_size, void* d_ws, size_t ws_size,
                              hipStream_t stream)
{
    const float* inputs  = (const float*)d_in[0];
    const float* hiddens = (const float*)d_in[1];
    const float* cells   = (const float*)d_in[2];
    const float* Wih[3]  = {(const float*)d_in[3], (const float*)d_in[7],  (const float*)d_in[11]};
    const float* Whh[3]  = {(const float*)d_in[4], (const float*)d_in[8],  (const float*)d_in[12]};
    const float* bih[3]  = {(const float*)d_in[5], (const float*)d_in[9],  (const float*)d_in[13]};
    const float* bhh[3]  = {(const float*)d_in[6], (const float*)d_in[10], (const float*)d_in[14]};
    const float* fc_w    = (const float*)d_in[15];
    const float* fc_b    = (const float*)d_in[16];
    float* out = (float*)d_out;

    // ---- workspace carve-up ----
    char* p = (char*)d_ws;
    auto take = [&](size_t bytes) -> void* {
        void* r = p; p += (bytes + 255) & ~(size_t)255; return r;
    };
    const int Kl[3]  = {K0P, K12, K12};
    const int Kin[3] = {IN_DIM, H_DIM, H_DIM};
    u16* wcat[3];
    for (int l = 0; l < 3; ++l) wcat[l] = (u16*)take((size_t)GATES * Kl[l] * 2);
    u16* Ab[3][2];
    for (int l = 0; l < 3; ++l)
        for (int q = 0; q < 2; ++q) Ab[l][q] = (u16*)take((size_t)BATCH * Kl[l] * 2);
    u16*   fcwb = (u16*)take((size_t)IN_DIM * H_DIM * 2);
    float* bsum = (float*)take((size_t)3 * GATES * 4);
    float* cbuf = (float*)take((size_t)3 * BATCH * H_DIM * 4);
    if ((size_t)(p - (char*)d_ws) > ws_size) return;

    auto pack = [&](const float* s, int ss, u16* d, int ds, int rows, int cols) {
        long t8 = (long)rows * (cols / 8);
        convpack_k<<<(int)((t8 + 255) / 256), 256, 0, stream>>>(s, ss, d, ds, cols / 8, t8);
    };
    auto zero = [&](u16* d, int ds, int rows, int cols) {
        long t8 = (long)rows * (cols / 8);
        zero16_k<<<(int)((t8 + 255) / 256), 256, 0, stream>>>(d, ds, cols / 8, t8);
    };

    // weights -> bf16 concatenated [Wih | Whh | pad]
    for (int l = 0; l < 3; ++l) {
        pack(Wih[l], Kin[l], wcat[l],           Kl[l], GATES, Kin[l]);
        pack(Whh[l], H_DIM,  wcat[l] + Kin[l],  Kl[l], GATES, H_DIM);
    }
    zero(wcat[0] + IN_DIM + H_DIM, K0P, GATES, K0P - IN_DIM - H_DIM);
    pack(fc_w, H_DIM, fcwb, H_DIM, IN_DIM, H_DIM);

    // initial states (parity 0), x0, pads (both parities of layer0)
    for (int l = 0; l < 3; ++l)
        pack(hiddens + (size_t)l * BATCH * H_DIM, H_DIM,
             Ab[l][0] + Kin[l], Kl[l], BATCH, H_DIM);
    pack(inputs, T_STEPS * IN_DIM, Ab[0][0], K0P, BATCH, IN_DIM);   // x_0
    zero(Ab[0][0] + IN_DIM + H_DIM, K0P, BATCH, K0P - IN_DIM - H_DIM);
    zero(Ab[0][1] + IN_DIM + H_DIM, K0P, BATCH, K0P - IN_DIM - H_DIM);

    for (int l = 0; l < 3; ++l)
        add_k<<<16, 256, 0, stream>>>(bih[l], bhh[l], bsum + l * GATES, GATES);
    hipMemcpyAsync(cbuf, cells, (size_t)3 * BATCH * H_DIM * 4,
                   hipMemcpyDeviceToDevice, stream);

    // ---- recurrence ----
    for (int t = 0; t < T_STEPS; ++t) {
        const int pr = t & 1, pn = pr ^ 1;
        // layer 0: reads Ab[0][pr]; h0 -> Ab[0][pn].h and Ab[1][pr].x
        lstm_layer_k<<<256, 256, 0, stream>>>(
            Ab[0][pr], wcat[0], K0P, K0P / 64, bsum,
            cbuf,
            Ab[0][pn] + IN_DIM, K0P,
            Ab[1][pr], K12);
        // layer 1: h1 -> Ab[1][pn].h and Ab[2][pr].x
        lstm_layer_k<<<256, 256, 0, stream>>>(
            Ab[1][pr], wcat[1], K12, K12 / 64, bsum + GATES,
            cbuf + (size_t)BATCH * H_DIM,
            Ab[1][pn] + H_DIM, K12,
            Ab[2][pr], K12);
        // layer 2: h2 -> Ab[2][pn].h only
        lstm_layer_k<<<256, 256, 0, stream>>>(
            Ab[2][pr], wcat[2], K12, K12 / 64, bsum + 2 * GATES,
            cbuf + (size_t)2 * BATCH * H_DIM,
            Ab[2][pn] + H_DIM, K12,
            (u16*)nullptr, 0);
        // FC reads h2 (just written, parity pn); writes out[:,t,:] and x_{t+1}
        fc_k<<<BATCH, 128, 0, stream>>>(
            Ab[2][pn] + H_DIM, K12, fcwb, fc_b, out, Ab[0][pn], t);
    }
}